// Round 1
// 302.938 us; speedup vs baseline: 1.0047x; 1.0047x over previous
//
#include <hip/hip_runtime.h>
#include <stdint.h>

typedef __bf16 bf16;
typedef __attribute__((ext_vector_type(8))) __bf16 bf16x8;
typedef __attribute__((ext_vector_type(4))) __bf16 bf16x4;
typedef __attribute__((ext_vector_type(4))) short short4v;
typedef __attribute__((ext_vector_type(4))) float f32x4;

static constexpr int Bn = 2, Ln = 2048, DIMn = 2048, Hn = 32, KVn = 8, HDn = 64;
static constexpr int TS = 3072;  // fused qkv token stride (2048 q + 512 k + 512 v)

#if defined(__has_builtin)
#if __has_builtin(__builtin_amdgcn_exp2f)
#define EXP2(x) __builtin_amdgcn_exp2f(x)
#endif
#endif
#ifndef EXP2
#define EXP2(x) exp2f(x)
#endif

#define TO_LDS(p) ((__attribute__((address_space(3))) uint32_t*)(uintptr_t)(p))
#define TO_GLB(p) ((const __attribute__((address_space(1))) uint32_t*)(uintptr_t)(p))

// ---------------- fused cast fp32 -> bf16 for all 5 inputs ----------------
__global__ void cast_all(const float* __restrict__ x, const float* __restrict__ wq,
                         const float* __restrict__ wk, const float* __restrict__ wv,
                         const float* __restrict__ wo, bf16* __restrict__ xb,
                         bf16* __restrict__ wqkvb, bf16* __restrict__ wob) {
    size_t i = (size_t)(blockIdx.x * blockDim.x + threadIdx.x) * 4;
    const float* src;
    bf16* dst;
    if (i < 8388608) {
        src = x + i; dst = xb + i;
    } else if (i < 8388608 + 6291456) {
        size_t j = i - 8388608;
        dst = wqkvb + j;
        if (j < 4194304)      src = wq + j;
        else if (j < 5242880) src = wk + (j - 4194304);
        else                  src = wv + (j - 5242880);
    } else {
        size_t j = i - 14680064;
        src = wo + j; dst = wob + j;
    }
    float4 v = *(const float4*)src;
    bf16 o[4] = {(bf16)v.x, (bf16)v.y, (bf16)v.z, (bf16)v.w};
    *(uint64_t*)dst = *(uint64_t*)o;
}

// ---------------- RoPE in-place on K region of qkv (cols 2048..2559) ----------------
__global__ void rope_k(bf16* __restrict__ qkv, const float* __restrict__ fc) {
    int idx = blockIdx.x * blockDim.x + threadIdx.x;   // T * 8 * 32 = 1,048,576
    int i   = idx & 31;
    int kvh = (idx >> 5) & 7;
    int bl  = idx >> 8;
    int l   = bl & (Ln - 1);
    size_t base = (size_t)bl * TS + 2048 + kvh * 64 + 2 * i;
    float cr = fc[l * 32 + i];
    float sr = fc[65536 + l * 32 + i];
    float x0 = (float)qkv[base], x1 = (float)qkv[base + 1];
    qkv[base]     = (bf16)(x0 * cr - x1 * sr);
    qkv[base + 1] = (bf16)(x0 * sr + x1 * cr);
}

// ---------------- 256x256x64 8-wave phase-pipelined GEMM: C = A * B^T ----------------
// bf16 in, fp32 acc. 512 threads = 8 waves (2M x 4N), per-wave 128x64 output.
// LDS 128 KiB: double-buffered 256x64 A and B tiles. XOR-swizzled staging:
// global_load_lds writes linearly, so the *global source* chunk is pre-swizzled
// (lane&7)^(lane>>3); frag reads apply the matching (kk*4+q4)^(row&7).
// 4 phases per K-tile: p1 reads A(mh0)+B(nh0) frags -> MFMA quad (mh0,nh0);
// p2 reads A(mh1)+B(nh1) -> (mh1,nh1);  [buf now fully consumed]
// p3 issues tile k+2's A half-tiles into this buf -> MFMA (mh1,nh0);
// p4 issues k+2's B halves + counted s_waitcnt vmcnt(8) -> MFMA (mh0,nh1).
// vmcnt(8) leaves k+2's 8 loads in flight across the barrier (never drain to 0).
static __device__ __forceinline__ void barrier_f() {
    asm volatile("" ::: "memory");
    __builtin_amdgcn_s_barrier();
    asm volatile("" ::: "memory");
}

template <bool OUT_BF16>
__global__ __launch_bounds__(512, 2) void gemm256(const bf16* __restrict__ A,
                                                  const bf16* __restrict__ Bm,
                                                  void* __restrict__ C,
                                                  int M, int N, int K) {
    (void)M;
    __shared__ bf16 sA[2][256 * 64];
    __shared__ bf16 sB[2][256 * 64];
    const int t    = threadIdx.x;
    const int wave = t >> 6, lane = t & 63;
    const int q4 = lane >> 4, l16 = lane & 15;
    const int wm = wave >> 2, wn = wave & 3;
    const int r8  = lane >> 3;                 // row within 8-row chunk
    const int csw = ((lane & 7) ^ r8) * 8;     // pre-swizzled source col (elements)

    const size_t bm = (size_t)blockIdx.y * 256, bn = (size_t)blockIdx.x * 256;
    const bf16* pa = A  + (bm + (size_t)(wave * 16 + r8)) * K + csw;
    const bf16* pb = Bm + (bn + (size_t)(wave * 16 + r8)) * K + csw;
    const int NT = K >> 6;

#define STG(P, SX, cbuf, h, i, kt)                                                            \
    __builtin_amdgcn_global_load_lds(                                                          \
        TO_GLB(P + (size_t)((h) * 128 + (i) * 8) * K + (size_t)(kt) * 64),                     \
        TO_LDS(&SX[cbuf][((h) * 128 + wave * 16 + (i) * 8) * 64]), 16, 0, 0)

    // ---- prologue: stage tiles 0 (buf0) and 1 (buf1); tile0 = oldest 8 loads ----
#pragma unroll
    for (int kt = 0; kt < 2; ++kt)
#pragma unroll
        for (int h = 0; h < 2; ++h)
#pragma unroll
            for (int i = 0; i < 2; ++i) {
                STG(pa, sA, kt, h, i, kt);
                STG(pb, sB, kt, h, i, kt);
            }
    asm volatile("s_waitcnt vmcnt(8)" ::: "memory");   // tile0 landed, tile1 in flight
    __builtin_amdgcn_s_barrier();
    asm volatile("" ::: "memory");

    f32x4 acc[8][4] = {};
    bf16x8 af[8][2], bfr[4][2];

#define MMQ(m0, n0)                                                                            \
    _Pragma("unroll") for (int mi = 0; mi < 4; ++mi)                                           \
    _Pragma("unroll") for (int ni = 0; ni < 2; ++ni)                                           \
    _Pragma("unroll") for (int kk = 0; kk < 2; ++kk)                                           \
        acc[(m0) + mi][(n0) + ni] = __builtin_amdgcn_mfma_f32_16x16x32_bf16(                   \
            af[(m0) + mi][kk], bfr[(n0) + ni][kk], acc[(m0) + mi][(n0) + ni], 0, 0, 0)

    for (int k = 0; k < NT; ++k) {
        const int c = k & 1;
        const bf16* la = &sA[c][0];
        const bf16* lb = &sB[c][0];
        const int swz = (l16 & 7);

        // ---- phase 1: read A(mh0) + B(nh0) ----
#pragma unroll
        for (int mi = 0; mi < 4; ++mi)
#pragma unroll
            for (int kk = 0; kk < 2; ++kk)
                af[mi][kk] = *(const bf16x8*)(la + (wm * 128 + mi * 16 + l16) * 64 +
                                              ((kk * 4 + q4) ^ swz) * 8);
#pragma unroll
        for (int ni = 0; ni < 2; ++ni)
#pragma unroll
            for (int kk = 0; kk < 2; ++kk)
                bfr[ni][kk] = *(const bf16x8*)(lb + (wn * 64 + ni * 16 + l16) * 64 +
                                               ((kk * 4 + q4) ^ swz) * 8);
        barrier_f();
        __builtin_amdgcn_s_setprio(1);
        MMQ(0, 0);
        __builtin_amdgcn_s_setprio(0);
        barrier_f();

        // ---- phase 2: read A(mh1) + B(nh1) ----
#pragma unroll
        for (int mi = 0; mi < 4; ++mi)
#pragma unroll
            for (int kk = 0; kk < 2; ++kk)
                af[4 + mi][kk] = *(const bf16x8*)(la + (wm * 128 + (4 + mi) * 16 + l16) * 64 +
                                                  ((kk * 4 + q4) ^ swz) * 8);
#pragma unroll
        for (int ni = 0; ni < 2; ++ni)
#pragma unroll
            for (int kk = 0; kk < 2; ++kk)
                bfr[2 + ni][kk] = *(const bf16x8*)(lb + (wn * 64 + (2 + ni) * 16 + l16) * 64 +
                                                   ((kk * 4 + q4) ^ swz) * 8);
        barrier_f();
        __builtin_amdgcn_s_setprio(1);
        MMQ(4, 2);
        __builtin_amdgcn_s_setprio(0);
        barrier_f();   // <- all reads of buf c complete; buf c now safe to overwrite

        // ---- phase 3: issue tile k+2's A half-tiles into buf c ----
        if (k + 2 < NT) {
            STG(pa, sA, c, 0, 0, k + 2);
            STG(pa, sA, c, 0, 1, k + 2);
            STG(pa, sA, c, 1, 0, k + 2);
            STG(pa, sA, c, 1, 1, k + 2);
        }
        barrier_f();
        __builtin_amdgcn_s_setprio(1);
        MMQ(4, 0);
        __builtin_amdgcn_s_setprio(0);
        barrier_f();

        // ---- phase 4: issue tile k+2's B halves; counted wait for tile k+1 ----
        if (k + 2 < NT) {
            STG(pb, sB, c, 0, 0, k + 2);
            STG(pb, sB, c, 0, 1, k + 2);
            STG(pb, sB, c, 1, 0, k + 2);
            STG(pb, sB, c, 1, 1, k + 2);
            asm volatile("s_waitcnt vmcnt(8)" ::: "memory");  // k+1 landed; k+2 flying
        } else if (k == NT - 2) {
            asm volatile("s_waitcnt vmcnt(0)" ::: "memory");  // drain for last tile
        }
        barrier_f();
        __builtin_amdgcn_s_setprio(1);
        MMQ(0, 2);
        __builtin_amdgcn_s_setprio(0);
        barrier_f();
    }
#undef MMQ
#undef STG

    // ---- epilogue ----
#pragma unroll
    for (int mi = 0; mi < 8; ++mi)
#pragma unroll
        for (int ni = 0; ni < 4; ++ni)
#pragma unroll
            for (int r = 0; r < 4; ++r) {
                size_t row = bm + wm * 128 + mi * 16 + q4 * 4 + r;
                size_t col = bn + wn * 64 + ni * 16 + l16;
                if (OUT_BF16)
                    ((bf16*)C)[row * (size_t)N + col] = (bf16)acc[mi][ni][r];
                else
                    ((float*)C)[row * (size_t)N + col] = acc[mi][ni][r];
            }
}

// ---------------- flash attention: 4 waves = 2 heads x 2 q-halves, uniform pairs ----------------
// Grid = 512 blocks (16 qt-pairs x 2 head-pairs x 8 kvh x 2 b), 256 threads.
// Wave w: head kvh*4 + hp*2 + (w&1), q rows [(w>>1)*32, +32) of the tile, all 64 keys.
// Each block runs q-tiles (31-pair, pair): uniform 33 tile-iters. launch_bounds(256,2)
// -> no VGPR spill, 2 blocks/CU co-resident (one block's compute hides the other's
// barriers). Static-max softmax in log2 domain (scale*log2e folded into in-register
// Q-RoPE): p = exp2(s-12), l deferred to epilogue. K pre-roped; K/V register-prefetched.
__global__ __launch_bounds__(256, 2) void attn_kernel(const bf16* __restrict__ QKV,
                                                      const float* __restrict__ fc,
                                                      bf16* __restrict__ O) {
    constexpr int LDK = 72;
    __shared__ bf16 sK[64 * LDK];          // [key][hd]
    __shared__ bf16 sV[64 * LDK];          // transposed: [hd][key]
    const int t    = threadIdx.x;
    const int wave = t >> 6, lane = t & 63;
    const int q4 = lane >> 4, l16 = lane & 15;
    const int hidx = wave & 1, qh = wave >> 1;
    const int L = blockIdx.x;
    const int pair = L & 15, hp = (L >> 4) & 1, kvh = (L >> 5) & 7, b = L >> 8;
    const int h = kvh * 4 + hp * 2 + hidx;
    constexpr float SC = 0.125f * 1.44269504088896340736f;

    const bf16* kb = QKV + (size_t)(b * Ln) * TS + 2048 + kvh * 64;
    const bf16* vb = kb + 512;
    // staging maps (256 threads; R4-proven)
    const int krow = t >> 3;               // 0..31 (rows krow, krow+32)
    const int kc8  = (t & 7) * 8;
    const int vkey = t & 63, vhd0 = (t >> 6) * 16;

    for (int half = 0; half < 2; ++half) {
        const int qtile = half == 0 ? 31 - pair : pair;

        // ---- load Q fragments (2 groups of 16 rows), RoPE + scale in-register ----
        bf16x8 qf[2][2];
#pragma unroll
        for (int g2 = 0; g2 < 2; ++g2) {
            int ql = qtile * 64 + (qh * 2 + g2) * 16 + l16;
            const bf16* qp = QKV + (size_t)(b * Ln + ql) * TS + h * 64;
#pragma unroll
            for (int hc = 0; hc < 2; ++hc) {
                bf16x8 raw = *(const bf16x8*)(qp + hc * 32 + q4 * 8);
                float4 c4 = *(const float4*)(fc + ql * 32 + hc * 16 + q4 * 4);
                float4 s4 = *(const float4*)(fc + 65536 + ql * 32 + hc * 16 + q4 * 4);
                bf16x8 o;
#pragma unroll
                for (int m = 0; m < 4; ++m) {
                    float cr = ((const float*)&c4)[m], sr = ((const float*)&s4)[m];
                    float x0 = (float)raw[2 * m], x1 = (float)raw[2 * m + 1];
                    o[2 * m]     = (bf16)((x0 * cr - x1 * sr) * SC);
                    o[2 * m + 1] = (bf16)((x0 * sr + x1 * cr) * SC);
                }
                qf[g2][hc] = o;
            }
        }

        f32x4 o_acc[2][4] = {};
        float l_r[2] = {0.f, 0.f};

        // ---- prefetch tile 0 ----
        bf16x8 kreg[2], vreg[2];
#pragma unroll
        for (int p = 0; p < 2; ++p)
            kreg[p] = *(const bf16x8*)(kb + (size_t)(p * 32 + krow) * TS + kc8);
        {
            const bf16* v0 = vb + (size_t)vkey * TS + vhd0;
            vreg[0] = *(const bf16x8*)(v0);
            vreg[1] = *(const bf16x8*)(v0 + 8);
        }

        for (int kt = 0; kt <= qtile; ++kt) {
            // ---- write staged tile to LDS ----
#pragma unroll
            for (int p = 0; p < 2; ++p)
                *(float4*)(&sK[(p * 32 + krow) * LDK + kc8]) = *(float4*)&kreg[p];
            {
                bf16 vv[16];
                *(bf16x8*)(vv)     = vreg[0];
                *(bf16x8*)(vv + 8) = vreg[1];
#pragma unroll
                for (int j = 0; j < 16; ++j) sV[(vhd0 + j) * LDK + vkey] = vv[j];
            }
            __syncthreads();

            // ---- prefetch next tile ----
            if (kt < qtile) {
#pragma unroll
                for (int p = 0; p < 2; ++p)
                    kreg[p] = *(const bf16x8*)(kb + (size_t)((kt + 1) * 64 + p * 32 + krow) * TS + kc8);
                const bf16* v0 = vb + (size_t)((kt + 1) * 64 + vkey) * TS + vhd0;
                vreg[0] = *(const bf16x8*)(v0);
                vreg[1] = *(const bf16x8*)(v0 + 8);
            }

            // ---- fragments (shared across both q-groups) ----
            bf16x8 kf[4][2];
#pragma unroll
            for (int c = 0; c < 4; ++c)
#pragma unroll
                for (int hc = 0; hc < 2; ++hc)
                    kf[c][hc] = *(const bf16x8*)(&sK[(c * 16 + l16) * LDK + hc * 32 + q4 * 8]);
            short4v vf[4][4];
#pragma unroll
            for (int nc = 0; nc < 4; ++nc)
#pragma unroll
                for (int c = 0; c < 4; ++c)
                    vf[nc][c] = *(const short4v*)(&sV[(nc * 16 + l16) * LDK + c * 16 + q4 * 4]);

            const bool diag = (kt == qtile);
#pragma unroll
            for (int g2 = 0; g2 < 2; ++g2) {
                f32x4 s[4];
#pragma unroll
                for (int c = 0; c < 4; ++c) {
                    f32x4 a = {};
                    a = __builtin_amdgcn_mfma_f32_16x16x32_bf16(kf[c][0], qf[g2][0], a, 0, 0, 0);
                    a = __builtin_amdgcn_mfma_f32_16x16x32_bf16(kf[c][1], qf[g2][1], a, 0, 0, 0);
                    s[c] = a;
                }
                int qrow = qtile * 64 + (qh * 2 + g2) * 16 + l16;
                float lsum = 0.f;
                short4v pb4[4];
#pragma unroll
                for (int c = 0; c < 4; ++c)
#pragma unroll
                    for (int r = 0; r < 4; ++r) {
                        float p = EXP2(s[c][r] - 12.f);
                        if (diag && (kt * 64 + c * 16 + q4 * 4 + r > qrow)) p = 0.f;
                        lsum += p;
                        bf16 ph = (bf16)p;
                        pb4[c][r] = *(const short*)&ph;
                    }
                l_r[g2] += lsum;
#pragma unroll
                for (int nc = 0; nc < 4; ++nc)
#pragma unroll
                    for (int c = 0; c < 4; ++c)
                        o_acc[g2][nc] = __builtin_amdgcn_mfma_f32_16x16x16bf16_1k(
                            vf[nc][c], pb4[c], o_acc[g2][nc], 0, 0, 0);
            }
            __syncthreads();
        }

        // ---- epilogue: reduce l across q4 sub-lanes, normalize, store ----
#pragma unroll
        for (int g2 = 0; g2 < 2; ++g2) {
            float l = l_r[g2];
            l += __shfl_xor(l, 16, 64);
            l += __shfl_xor(l, 32, 64);
            float inv = 1.f / l;
            int qrow = qtile * 64 + (qh * 2 + g2) * 16 + l16;
            bf16* op = O + (size_t)(b * Ln + qrow) * (Hn * HDn) + h * 64;
#pragma unroll
            for (int nc = 0; nc < 4; ++nc) {
                bf16x4 o;
#pragma unroll
                for (int r = 0; r < 4; ++r) o[r] = (bf16)(o_acc[g2][nc][r] * inv);
                *(bf16x4*)(op + nc * 16 + q4 * 4) = o;
            }
        }
    }
}

// ---------------- launch ----------------
extern "C" void kernel_launch(void* const* d_in, const int* in_sizes, int n_in,
                              void* d_out, int out_size, void* d_ws, size_t ws_size,
                              hipStream_t stream) {
    const float* x  = (const float*)d_in[0];
    const float* fc = (const float*)d_in[1];
    const float* wq = (const float*)d_in[2];
    const float* wk = (const float*)d_in[3];
    const float* wv = (const float*)d_in[4];
    const float* wo = (const float*)d_in[5];
    float* out = (float*)d_out;

    const size_t T = (size_t)Bn * Ln;  // 4096 tokens
    char* p = (char*)d_ws;
    bf16* xb    = (bf16*)p; p += T * DIMn * 2;
    bf16* wqkvb = (bf16*)p; p += (size_t)TS * DIMn * 2;
    bf16* wob   = (bf16*)p; p += (size_t)DIMn * Hn * HDn * 2;
    bf16* qkv   = (bf16*)p; p += T * TS * 2;
    bf16* ao    = (bf16*)p; p += T * Hn * HDn * 2;

    cast_all<<<dim3(18432), dim3(256), 0, stream>>>(x, wq, wk, wv, wo, xb, wqkvb, wob);

    // fused QKV projection: [4096, 3072] = xb[4096,2048] * wqkv[3072,2048]^T
    gemm256<true><<<dim3(TS / 256, 16), dim3(512), 0, stream>>>(xb, wqkvb, qkv, 4096, TS, 2048);

    // pre-rope K region (Q roped in-register inside attn)
    rope_k<<<dim3(4096), dim3(256), 0, stream>>>(qkv, fc);

    // attention: 512 uniform blocks, 4 waves each, 2 blocks/CU
    attn_kernel<<<dim3(512), dim3(256), 0, stream>>>(qkv, fc, ao);

    // output projection: [4096, 2048] = ao[4096,2048] * wo[2048,2048]^T
    gemm256<false><<<dim3(2048 / 256, 16), dim3(512), 0, stream>>>(ao, wob, out, 4096, 2048, 2048);
}

// Round 2
// 270.348 us; speedup vs baseline: 1.1258x; 1.1205x over previous
//
#include <hip/hip_runtime.h>
#include <stdint.h>

typedef __bf16 bf16;
typedef __attribute__((ext_vector_type(8))) __bf16 bf16x8;
typedef __attribute__((ext_vector_type(4))) __bf16 bf16x4;
typedef __attribute__((ext_vector_type(4))) short short4v;
typedef __attribute__((ext_vector_type(4))) float f32x4;

static constexpr int Bn = 2, Ln = 2048, DIMn = 2048, Hn = 32, KVn = 8, HDn = 64;
static constexpr int TS = 3072;  // fused qkv token stride (2048 q + 512 k + 512 v)

#if defined(__has_builtin)
#if __has_builtin(__builtin_amdgcn_exp2f)
#define EXP2(x) __builtin_amdgcn_exp2f(x)
#endif
#endif
#ifndef EXP2
#define EXP2(x) exp2f(x)
#endif

#define TO_LDS(p) ((__attribute__((address_space(3))) uint32_t*)(uintptr_t)(p))
#define TO_GLB(p) ((const __attribute__((address_space(1))) uint32_t*)(uintptr_t)(p))

// ---------------- fused cast fp32 -> bf16 for all 5 inputs ----------------
__global__ void cast_all(const float* __restrict__ x, const float* __restrict__ wq,
                         const float* __restrict__ wk, const float* __restrict__ wv,
                         const float* __restrict__ wo, bf16* __restrict__ xb,
                         bf16* __restrict__ wqkvb, bf16* __restrict__ wob) {
    size_t i = (size_t)(blockIdx.x * blockDim.x + threadIdx.x) * 4;
    const float* src;
    bf16* dst;
    if (i < 8388608) {
        src = x + i; dst = xb + i;
    } else if (i < 8388608 + 6291456) {
        size_t j = i - 8388608;
        dst = wqkvb + j;
        if (j < 4194304)      src = wq + j;
        else if (j < 5242880) src = wk + (j - 4194304);
        else                  src = wv + (j - 5242880);
    } else {
        size_t j = i - 14680064;
        src = wo + j; dst = wob + j;
    }
    float4 v = *(const float4*)src;
    bf16 o[4] = {(bf16)v.x, (bf16)v.y, (bf16)v.z, (bf16)v.w};
    *(uint64_t*)dst = *(uint64_t*)o;
}

// ---------------- RoPE in-place on K region of qkv (cols 2048..2559) ----------------
__global__ void rope_k(bf16* __restrict__ qkv, const float* __restrict__ fc) {
    int idx = blockIdx.x * blockDim.x + threadIdx.x;   // T * 8 * 32 = 1,048,576
    int i   = idx & 31;
    int kvh = (idx >> 5) & 7;
    int bl  = idx >> 8;
    int l   = bl & (Ln - 1);
    size_t base = (size_t)bl * TS + 2048 + kvh * 64 + 2 * i;
    float cr = fc[l * 32 + i];
    float sr = fc[65536 + l * 32 + i];
    float x0 = (float)qkv[base], x1 = (float)qkv[base + 1];
    qkv[base]     = (bf16)(x0 * cr - x1 * sr);
    qkv[base + 1] = (bf16)(x0 * sr + x1 * cr);
}

// ---------------- BM x BN x 64 8-wave pipelined GEMM: C = A * B^T ----------------
// bf16 in, fp32 acc. 512 threads = 8 waves (2M x 4N), per-wave (BM/2)x(BN/4).
// Swizzled staging: global_load_lds writes linearly, so the *global source* is
// pre-swizzled col ((lane&7)^(lane>>3))*8; frag reads apply ((kk*4+q4)^(row&7)).
// Schedule per K-tile: [reads A-low, B-all, A-high | MFMA all] with NO intra-tile
// barriers (compiler emits fine-grained lgkmcnt -> LDS drain overlaps MFMA), then
// barrier / stage tile k+2 into this buffer / counted vmcnt(LPT) (tile k+1 landed,
// k+2 stays in flight) / barrier. Grids chosen so grid == 256 blocks (1/CU).
static __device__ __forceinline__ void barrier_f() {
    asm volatile("" ::: "memory");
    __builtin_amdgcn_s_barrier();
    asm volatile("" ::: "memory");
}

template <int N>
static __device__ __forceinline__ void waitcnt_vm() {
    if constexpr (N == 0) asm volatile("s_waitcnt vmcnt(0)" ::: "memory");
    else if constexpr (N == 6) asm volatile("s_waitcnt vmcnt(6)" ::: "memory");
    else if constexpr (N == 7) asm volatile("s_waitcnt vmcnt(7)" ::: "memory");
    else static_assert(N == 0 || N == 6 || N == 7, "add vmcnt literal");
}

template <int BM, int BN, bool OUT_BF16>
__global__ __launch_bounds__(512, 2) void gemm256(const bf16* __restrict__ A,
                                                  const bf16* __restrict__ Bm,
                                                  void* __restrict__ C,
                                                  int M, int N, int K) {
    (void)M;
    constexpr int MI = BM / 32;          // 16-row frags per wave (BM/2 rows)
    constexpr int NI = BN / 64;          // 16-col frags per wave (BN/4 cols)
    constexpr int AJ = BM / 64, BJ = BN / 64, LPT = AJ + BJ;
    __shared__ bf16 sA[2][BM * 64];
    __shared__ bf16 sB[2][BN * 64];
    const int t    = threadIdx.x;
    const int wave = t >> 6, lane = t & 63;
    const int q4 = lane >> 4, l16 = lane & 15;
    const int wm = wave >> 2, wn = wave & 3;
    const int r8l = lane >> 3;
    const int csw = ((lane & 7) ^ r8l) * 8;   // pre-swizzled source col (elements)

    const size_t bm = (size_t)blockIdx.y * BM, bn = (size_t)blockIdx.x * BN;
    const bf16* pa = A  + (bm + (size_t)(wave * 8 + r8l)) * K + csw;
    const bf16* pb = Bm + (bn + (size_t)(wave * 8 + r8l)) * K + csw;
    const int NT = K >> 6;

    // stage one 64-row chunk j of a 64-col K-slice kt into buf: wave w covers
    // rows j*64 + w*8 + (lane>>3); LDS dest linear (wave-uniform base + lane*16B)
#define STGA(buf, kt)                                                                          \
    _Pragma("unroll") for (int j = 0; j < AJ; ++j)                                             \
        __builtin_amdgcn_global_load_lds(TO_GLB(pa + (size_t)j * 64 * K + (size_t)(kt) * 64),  \
                                         TO_LDS(&sA[buf][(j * 64 + wave * 8) * 64]), 16, 0, 0)
#define STGB(buf, kt)                                                                          \
    _Pragma("unroll") for (int j = 0; j < BJ; ++j)                                             \
        __builtin_amdgcn_global_load_lds(TO_GLB(pb + (size_t)j * 64 * K + (size_t)(kt) * 64),  \
                                         TO_LDS(&sB[buf][(j * 64 + wave * 8) * 64]), 16, 0, 0)

    // ---- prologue: stage tiles 0 (buf0, oldest LPT) and 1 (buf1) ----
    STGA(0, 0); STGB(0, 0);
    STGA(1, 1); STGB(1, 1);
    waitcnt_vm<LPT>();                         // tile0 landed, tile1 in flight
    __builtin_amdgcn_s_barrier();
    asm volatile("" ::: "memory");

    f32x4 acc[MI][NI] = {};
    bf16x8 af[MI][2], bfr[NI][2];

    for (int k = 0; k < NT; ++k) {
        const int c = k & 1;
        const bf16* la = &sA[c][0];
        const bf16* lb = &sB[c][0];
        const int sw = (l16 & 7);

        // ---- reads: A-low, B-all, A-high (no intra-tile barriers) ----
#pragma unroll
        for (int mi = 0; mi < MI / 2; ++mi)
#pragma unroll
            for (int kk = 0; kk < 2; ++kk)
                af[mi][kk] = *(const bf16x8*)(la + (wm * (BM / 2) + mi * 16 + l16) * 64 +
                                              ((kk * 4 + q4) ^ sw) * 8);
#pragma unroll
        for (int ni = 0; ni < NI; ++ni)
#pragma unroll
            for (int kk = 0; kk < 2; ++kk)
                bfr[ni][kk] = *(const bf16x8*)(lb + (wn * (BN / 4) + ni * 16 + l16) * 64 +
                                               ((kk * 4 + q4) ^ sw) * 8);
#pragma unroll
        for (int mi = MI / 2; mi < MI; ++mi)
#pragma unroll
            for (int kk = 0; kk < 2; ++kk)
                af[mi][kk] = *(const bf16x8*)(la + (wm * (BM / 2) + mi * 16 + l16) * 64 +
                                              ((kk * 4 + q4) ^ sw) * 8);

        // ---- MFMA: m-low first (its operands arrive first); compiler inserts
        //      partial lgkmcnt so A-high drain overlaps the m-low cluster ----
        __builtin_amdgcn_s_setprio(1);
#pragma unroll
        for (int mi = 0; mi < MI; ++mi)
#pragma unroll
            for (int ni = 0; ni < NI; ++ni)
#pragma unroll
                for (int kk = 0; kk < 2; ++kk)
                    acc[mi][ni] = __builtin_amdgcn_mfma_f32_16x16x32_bf16(
                        af[mi][kk], bfr[ni][kk], acc[mi][ni], 0, 0, 0);
        __builtin_amdgcn_s_setprio(0);

        barrier_f();   // all waves done reading buf c -> safe to overwrite

        if (k + 2 < NT) {
            STGA(c, k + 2);
            STGB(c, k + 2);
            waitcnt_vm<LPT>();                 // tile k+1 landed; k+2 flying
        } else if (k == NT - 2) {
            waitcnt_vm<0>();                   // drain for last tile
        }
        barrier_f();   // next tile's buffer ready for all waves
    }
#undef STGA
#undef STGB

    // ---- epilogue ----
#pragma unroll
    for (int mi = 0; mi < MI; ++mi)
#pragma unroll
        for (int ni = 0; ni < NI; ++ni)
#pragma unroll
            for (int r = 0; r < 4; ++r) {
                size_t row = bm + wm * (BM / 2) + mi * 16 + q4 * 4 + r;
                size_t col = bn + wn * (BN / 4) + ni * 16 + l16;
                if (OUT_BF16)
                    ((bf16*)C)[row * (size_t)N + col] = (bf16)acc[mi][ni][r];
                else
                    ((float*)C)[row * (size_t)N + col] = acc[mi][ni][r];
            }
}

// ---------------- flash attention: 4 waves = 2 heads x 2 q-halves, uniform pairs ----------------
// Grid = 512 blocks (16 qt-pairs x 2 head-pairs x 8 kvh x 2 b), 256 threads.
// Wave w: head kvh*4 + hp*2 + (w&1), q rows [(w>>1)*32, +32) of the tile, all 64 keys.
// Each block runs q-tiles (31-pair, pair): uniform 33 tile-iters. launch_bounds(256,2)
// -> no VGPR spill, 2 blocks/CU co-resident (one block's compute hides the other's
// barriers). Static-max softmax in log2 domain (scale*log2e folded into in-register
// Q-RoPE): p = exp2(s-12), l deferred to epilogue. K pre-roped; K/V register-prefetched.
__global__ __launch_bounds__(256, 2) void attn_kernel(const bf16* __restrict__ QKV,
                                                      const float* __restrict__ fc,
                                                      bf16* __restrict__ O) {
    constexpr int LDK = 72;
    __shared__ bf16 sK[64 * LDK];          // [key][hd]
    __shared__ bf16 sV[64 * LDK];          // transposed: [hd][key]
    const int t    = threadIdx.x;
    const int wave = t >> 6, lane = t & 63;
    const int q4 = lane >> 4, l16 = lane & 15;
    const int hidx = wave & 1, qh = wave >> 1;
    const int L = blockIdx.x;
    const int pair = L & 15, hp = (L >> 4) & 1, kvh = (L >> 5) & 7, b = L >> 8;
    const int h = kvh * 4 + hp * 2 + hidx;
    constexpr float SC = 0.125f * 1.44269504088896340736f;

    const bf16* kb = QKV + (size_t)(b * Ln) * TS + 2048 + kvh * 64;
    const bf16* vb = kb + 512;
    // staging maps (256 threads; R4-proven)
    const int krow = t >> 3;               // 0..31 (rows krow, krow+32)
    const int kc8  = (t & 7) * 8;
    const int vkey = t & 63, vhd0 = (t >> 6) * 16;

    for (int half = 0; half < 2; ++half) {
        const int qtile = half == 0 ? 31 - pair : pair;

        // ---- load Q fragments (2 groups of 16 rows), RoPE + scale in-register ----
        bf16x8 qf[2][2];
#pragma unroll
        for (int g2 = 0; g2 < 2; ++g2) {
            int ql = qtile * 64 + (qh * 2 + g2) * 16 + l16;
            const bf16* qp = QKV + (size_t)(b * Ln + ql) * TS + h * 64;
#pragma unroll
            for (int hc = 0; hc < 2; ++hc) {
                bf16x8 raw = *(const bf16x8*)(qp + hc * 32 + q4 * 8);
                float4 c4 = *(const float4*)(fc + ql * 32 + hc * 16 + q4 * 4);
                float4 s4 = *(const float4*)(fc + 65536 + ql * 32 + hc * 16 + q4 * 4);
                bf16x8 o;
#pragma unroll
                for (int m = 0; m < 4; ++m) {
                    float cr = ((const float*)&c4)[m], sr = ((const float*)&s4)[m];
                    float x0 = (float)raw[2 * m], x1 = (float)raw[2 * m + 1];
                    o[2 * m]     = (bf16)((x0 * cr - x1 * sr) * SC);
                    o[2 * m + 1] = (bf16)((x0 * sr + x1 * cr) * SC);
                }
                qf[g2][hc] = o;
            }
        }

        f32x4 o_acc[2][4] = {};
        float l_r[2] = {0.f, 0.f};

        // ---- prefetch tile 0 ----
        bf16x8 kreg[2], vreg[2];
#pragma unroll
        for (int p = 0; p < 2; ++p)
            kreg[p] = *(const bf16x8*)(kb + (size_t)(p * 32 + krow) * TS + kc8);
        {
            const bf16* v0 = vb + (size_t)vkey * TS + vhd0;
            vreg[0] = *(const bf16x8*)(v0);
            vreg[1] = *(const bf16x8*)(v0 + 8);
        }

        for (int kt = 0; kt <= qtile; ++kt) {
            // ---- write staged tile to LDS ----
#pragma unroll
            for (int p = 0; p < 2; ++p)
                *(float4*)(&sK[(p * 32 + krow) * LDK + kc8]) = *(float4*)&kreg[p];
            {
                bf16 vv[16];
                *(bf16x8*)(vv)     = vreg[0];
                *(bf16x8*)(vv + 8) = vreg[1];
#pragma unroll
                for (int j = 0; j < 16; ++j) sV[(vhd0 + j) * LDK + vkey] = vv[j];
            }
            __syncthreads();

            // ---- prefetch next tile ----
            if (kt < qtile) {
#pragma unroll
                for (int p = 0; p < 2; ++p)
                    kreg[p] = *(const bf16x8*)(kb + (size_t)((kt + 1) * 64 + p * 32 + krow) * TS + kc8);
                const bf16* v0 = vb + (size_t)((kt + 1) * 64 + vkey) * TS + vhd0;
                vreg[0] = *(const bf16x8*)(v0);
                vreg[1] = *(const bf16x8*)(v0 + 8);
            }

            // ---- fragments (shared across both q-groups) ----
            bf16x8 kf[4][2];
#pragma unroll
            for (int c = 0; c < 4; ++c)
#pragma unroll
                for (int hc = 0; hc < 2; ++hc)
                    kf[c][hc] = *(const bf16x8*)(&sK[(c * 16 + l16) * LDK + hc * 32 + q4 * 8]);
            short4v vf[4][4];
#pragma unroll
            for (int nc = 0; nc < 4; ++nc)
#pragma unroll
                for (int c = 0; c < 4; ++c)
                    vf[nc][c] = *(const short4v*)(&sV[(nc * 16 + l16) * LDK + c * 16 + q4 * 4]);

            const bool diag = (kt == qtile);
#pragma unroll
            for (int g2 = 0; g2 < 2; ++g2) {
                f32x4 s[4];
#pragma unroll
                for (int c = 0; c < 4; ++c) {
                    f32x4 a = {};
                    a = __builtin_amdgcn_mfma_f32_16x16x32_bf16(kf[c][0], qf[g2][0], a, 0, 0, 0);
                    a = __builtin_amdgcn_mfma_f32_16x16x32_bf16(kf[c][1], qf[g2][1], a, 0, 0, 0);
                    s[c] = a;
                }
                int qrow = qtile * 64 + (qh * 2 + g2) * 16 + l16;
                float lsum = 0.f;
                short4v pb4[4];
#pragma unroll
                for (int c = 0; c < 4; ++c)
#pragma unroll
                    for (int r = 0; r < 4; ++r) {
                        float p = EXP2(s[c][r] - 12.f);
                        if (diag && (kt * 64 + c * 16 + q4 * 4 + r > qrow)) p = 0.f;
                        lsum += p;
                        bf16 ph = (bf16)p;
                        pb4[c][r] = *(const short*)&ph;
                    }
                l_r[g2] += lsum;
#pragma unroll
                for (int nc = 0; nc < 4; ++nc)
#pragma unroll
                    for (int c = 0; c < 4; ++c)
                        o_acc[g2][nc] = __builtin_amdgcn_mfma_f32_16x16x16bf16_1k(
                            vf[nc][c], pb4[c], o_acc[g2][nc], 0, 0, 0);
            }
            __syncthreads();
        }

        // ---- epilogue: reduce l across q4 sub-lanes, normalize, store ----
#pragma unroll
        for (int g2 = 0; g2 < 2; ++g2) {
            float l = l_r[g2];
            l += __shfl_xor(l, 16, 64);
            l += __shfl_xor(l, 32, 64);
            float inv = 1.f / l;
            int qrow = qtile * 64 + (qh * 2 + g2) * 16 + l16;
            bf16* op = O + (size_t)(b * Ln + qrow) * (Hn * HDn) + h * 64;
#pragma unroll
            for (int nc = 0; nc < 4; ++nc) {
                bf16x4 o;
#pragma unroll
                for (int r = 0; r < 4; ++r) o[r] = (bf16)(o_acc[g2][nc][r] * inv);
                *(bf16x4*)(op + nc * 16 + q4 * 4) = o;
            }
        }
    }
}

// ---------------- launch ----------------
extern "C" void kernel_launch(void* const* d_in, const int* in_sizes, int n_in,
                              void* d_out, int out_size, void* d_ws, size_t ws_size,
                              hipStream_t stream) {
    const float* x  = (const float*)d_in[0];
    const float* fc = (const float*)d_in[1];
    const float* wq = (const float*)d_in[2];
    const float* wk = (const float*)d_in[3];
    const float* wv = (const float*)d_in[4];
    const float* wo = (const float*)d_in[5];
    float* out = (float*)d_out;

    const size_t T = (size_t)Bn * Ln;  // 4096 tokens
    char* p = (char*)d_ws;
    bf16* xb    = (bf16*)p; p += T * DIMn * 2;
    bf16* wqkvb = (bf16*)p; p += (size_t)TS * DIMn * 2;
    bf16* wob   = (bf16*)p; p += (size_t)DIMn * Hn * HDn * 2;
    bf16* qkv   = (bf16*)p; p += T * TS * 2;
    bf16* ao    = (bf16*)p; p += T * Hn * HDn * 2;

    cast_all<<<dim3(18432), dim3(256), 0, stream>>>(x, wq, wk, wv, wo, xb, wqkvb, wob);

    // fused QKV projection: [4096, 3072] = xb * wqkv^T — 256x192 tiles -> 16x16 = 256 blocks
    gemm256<256, 192, true><<<dim3(TS / 192, 4096 / 256), dim3(512), 0, stream>>>(
        xb, wqkvb, qkv, 4096, TS, 2048);

    // pre-rope K region (Q roped in-register inside attn)
    rope_k<<<dim3(4096), dim3(256), 0, stream>>>(qkv, fc);

    // attention: 512 uniform blocks, 4 waves each, 2 blocks/CU
    attn_kernel<<<dim3(512), dim3(256), 0, stream>>>(qkv, fc, ao);

    // output projection: [4096, 2048] = ao * wo^T — 128x256 tiles -> 8x32 = 256 blocks
    gemm256<128, 256, false><<<dim3(2048 / 256, 4096 / 128), dim3(512), 0, stream>>>(
        ao, wob, out, 4096, 2048, 2048);
}